// Round 2
// baseline (76802.612 us; speedup 1.0000x reference)
//
#include <hip/hip_runtime.h>
#include <stdint.h>

#define B_   128
#define T_   4096
#define F_   64
#define H0_  77
#define H1_  51
#define H2_  128
#define K0_  141
#define K1_  128
#define K2_  179
#define NPMAX 90            // pairs per weight row (covers K2=179 with zero pad)
#define NP0   71
#define NP1   64
#define NP2   90
#define ZS1   192           // float offsets of z rows in LDS (stride 192 floats)
#define ZS2   384

typedef _Float16 half2_t __attribute__((ext_vector_type(2)));

__device__ inline float bf2f(unsigned short v) {
    unsigned u = ((unsigned)v) << 16;
    return __builtin_bit_cast(float, u);
}
__device__ inline unsigned short f2bf(float f) {
    unsigned u = __builtin_bit_cast(unsigned, f);
    unsigned r = (u + 0x7FFFu + ((u >> 16) & 1u)) >> 16;   // RNE, finite values
    return (unsigned short)r;
}
__device__ inline uint32_t packh2(float a, float b) {
    half2_t h; h.x = (_Float16)a; h.y = (_Float16)b;
    return __builtin_bit_cast(uint32_t, h);
}
__device__ inline half2_t u2h(uint32_t u) { return __builtin_bit_cast(half2_t, u); }

// dt: 0 = fp32, 1 = bf16, 2 = fp16
__device__ inline float ldany(const void* p, size_t i, int dt) {
    if (dt == 0) return ((const float*)p)[i];
    if (dt == 1) return bf2f(((const unsigned short*)p)[i]);
    return (float)((const _Float16*)p)[i];
}
__device__ inline void stout(void* p, size_t i, float v, int dt) {
    if (dt == 0)      ((float*)p)[i] = v;
    else if (dt == 1) ((unsigned short*)p)[i] = f2bf(v);
    else              ((_Float16*)p)[i] = (_Float16)v;
}

__device__ inline float sigm_f(float x) { return 1.0f / (1.0f + __expf(-x)); }
__device__ inline float tanh_f(float x) { return 2.0f / (1.0f + __expf(-2.0f * x)) - 1.0f; }

struct Params { const void* in[29]; };

// fmaf((float)f16, f32, f32) -> v_fma_mix_f32; products exact, fp32 accumulate.
#define DOT(NP, ZP) do {                                                        \
    const float* zz = (ZP);                                                     \
    _Pragma("unroll")                                                           \
    for (int i = 0; i < (NP); ++i) {                                            \
        half2_t p1 = u2h(wp1[i]), p2 = u2h(wp2[i]), pc = u2h(wpc[i]);           \
        float za = zz[2 * i], zb = zz[2 * i + 1];                               \
        a1 = fmaf((float)p1.x, za, a1); a1 = fmaf((float)p1.y, zb, a1);         \
        a2 = fmaf((float)p2.x, za, a2); a2 = fmaf((float)p2.y, zb, a2);         \
        ac = fmaf((float)pc.x, za, ac); ac = fmaf((float)pc.y, zb, ac);         \
    } } while (0)

__global__ __launch_bounds__(256, 1)
void liquid_cfc_kernel(Params p, void* __restrict__ outp) {
    const int tid = threadIdx.x;
    const int b   = blockIdx.x;

    // lane -> (layer, unit): [0,77)=L0, [77,128)=L1, [128,256)=L2
    int lay, u, k;
    if (tid < H0_)            { lay = 0; u = tid;        k = K0_; }
    else if (tid < H0_ + H1_) { lay = 1; u = tid - H0_;  k = K1_; }
    else                      { lay = 2; u = tid - 128;  k = K2_; }

    const void* xp  = p.in[0];
    const void* h0p = p.in[1];
    // setup_inputs dict order per layer: m, W1, W2, Wa, Wb, b1, b2, ba, bb
    const void* Mp  = p.in[2 + 9 * lay + 0];
    const void* W1p = p.in[2 + 9 * lay + 1];
    const void* W2p = p.in[2 + 9 * lay + 2];
    const void* Wap = p.in[2 + 9 * lay + 3];
    const void* Wbp = p.in[2 + 9 * lay + 4];
    const void* B1p = p.in[2 + 9 * lay + 5];
    const void* B2p = p.in[2 + 9 * lay + 6];
    const void* Bap = p.in[2 + 9 * lay + 7];
    const void* Bbp = p.in[2 + 9 * lay + 8];

    // 3-way dtype probe on mask m_0 (values exactly 0.0 / 1.0):
    //   fp32: u16 halves = (0,0) or (0,0x3F80) -> even-index u16 all zero
    //   bf16: u16 in {0x0000, 0x3F80} at every index
    //   fp16: u16 in {0x0000, 0x3C00}
    int dt;
    {
        const unsigned short* q = (const unsigned short*)p.in[2];
        bool anyf16 = false, lowNZ = false;
        for (int i = 0; i < 64; ++i) {
            unsigned short v = q[i];
            if (v == 0x3C00) anyf16 = true;
            if ((i & 1) == 0 && v != 0) lowNZ = true;
        }
        dt = anyf16 ? 2 : (lowNZ ? 1 : 0);
    }

    // one-time: load + mask + fold (Wa+Wb), pack rows as f16 pairs in VGPRs
    const int rowoff = u * k;
    uint32_t wp1[NPMAX], wp2[NPMAX], wpc[NPMAX];
#pragma unroll
    for (int i = 0; i < NPMAX; ++i) {
        const int j0 = 2 * i, j1 = 2 * i + 1;
        float m0 = 0.f, m1 = 0.f, v1a = 0.f, v1b = 0.f, v2a = 0.f, v2b = 0.f,
              vca = 0.f, vcb = 0.f;
        if (j0 < k) {
            m0  = ldany(Mp,  rowoff + j0, dt);
            v1a = ldany(W1p, rowoff + j0, dt);
            v2a = ldany(W2p, rowoff + j0, dt);
            vca = ldany(Wap, rowoff + j0, dt) + ldany(Wbp, rowoff + j0, dt);
        }
        if (j1 < k) {
            m1  = ldany(Mp,  rowoff + j1, dt);
            v1b = ldany(W1p, rowoff + j1, dt);
            v2b = ldany(W2p, rowoff + j1, dt);
            vcb = ldany(Wap, rowoff + j1, dt) + ldany(Wbp, rowoff + j1, dt);
        }
        wp1[i] = packh2(v1a * m0, v1b * m1);
        wp2[i] = packh2(v2a * m0, v2b * m1);
        wpc[i] = packh2(vca * m0, vcb * m1);
    }

    const float bias1 = ldany(B1p, u, dt);
    const float bias2 = ldany(B2p, u, dt);
    const float biasc = ldany(Bap, u, dt) + ldany(Bbp, u, dt);
    float hcur = ldany(h0p, (size_t)b * 256 + tid, dt);

    // z rows (fp32, stride 192): z0=[x(64)|h0(77)] z1=[h0'(77)|h1(51)] z2=[h1'(51)|h2(128)]
    __shared__ float zs[3 * 192];
    for (int i = tid; i < 3 * 192; i += 256) zs[i] = 0.f;
    __syncthreads();

    const int hslot = (lay == 0 ? 64 : (lay == 1 ? ZS1 + 77 : ZS2 + 51)) + u;
    zs[hslot] = hcur;

    const bool isx = (tid >= 128) && (tid < 160);   // L2 lanes u<32: x staging duty
    const int  xj  = tid - 128;
    const size_t xbase = (size_t)b * T_ * F_;
    const size_t obase = (size_t)b * T_ * H2_;
    if (isx) {
        zs[2 * xj]     = ldany(xp, xbase + 2 * xj, dt);
        zs[2 * xj + 1] = ldany(xp, xbase + 2 * xj + 1, dt);
    }
    __syncthreads();

    for (int t = 0; t < T_; ++t) {
        float hn = 0.f, xf0 = 0.f, xf1 = 0.f;
        const bool px = isx && (t + 1 < T_);
        if (px) {  // prefetch x(t+1); written to z0.x at end of step
            size_t xi = xbase + (size_t)(t + 1) * F_ + 2 * xj;
            xf0 = ldany(xp, xi, dt);
            xf1 = ldany(xp, xi + 1, dt);
        }

        // Phase A: L0 computes h0(t+1) from z0=[x(t), h0(t)]
        if (lay == 0) {
            float a1 = bias1, a2 = bias2, ac = biasc;
            DOT(NP0, &zs[0]);
            float ff1 = tanh_f(a1), ff2 = tanh_f(a2), ti = sigm_f(ac);
            hn = ff1 + ti * (ff2 - ff1);
        }
        __syncthreads();                                   // (1) A reads done
        if (lay == 0) { zs[ZS1 + u] = hn; zs[64 + u] = hn; hcur = hn; }
        __syncthreads();                                   // (2) A writes visible

        // Phase B: L1 from z1=[h0(t+1), h1(t)]
        if (lay == 1) {
            float a1 = bias1, a2 = bias2, ac = biasc;
            DOT(NP1, &zs[ZS1]);
            float ff1 = tanh_f(a1), ff2 = tanh_f(a2), ti = sigm_f(ac);
            hn = ff1 + ti * (ff2 - ff1);
        }
        __syncthreads();                                   // (3) B reads done
        if (lay == 1) { zs[ZS2 + u] = hn; zs[ZS1 + 77 + u] = hn; hcur = hn; }
        __syncthreads();                                   // (4) B writes visible

        // Phase C: L2 from z2=[h1(t+1), h2(t)]; y_t = h2(t+1)
        if (lay == 2) {
            float a1 = bias1, a2 = bias2, ac = biasc;
            DOT(NP2, &zs[ZS2]);
            float ff1 = tanh_f(a1), ff2 = tanh_f(a2), ti = sigm_f(ac);
            hn = ff1 + ti * (ff2 - ff1);
        }
        __syncthreads();                                   // (5) C reads done
        if (lay == 2) {
            zs[ZS2 + 51 + u] = hn; hcur = hn;
            stout(outp, obase + (size_t)t * H2_ + u, hn, dt);
        }
        if (px) { zs[2 * xj] = xf0; zs[2 * xj + 1] = xf1; }  // z0.x for t+1
        __syncthreads();                                   // (6) step complete
    }

    // final hidden state hx = [L0 | L1 | L2] == lane order
    stout(outp, (size_t)B_ * T_ * H2_ + (size_t)b * 256 + tid, hcur, dt);
}

extern "C" void kernel_launch(void* const* d_in, const int* in_sizes, int n_in,
                              void* d_out, int out_size, void* d_ws, size_t ws_size,
                              hipStream_t stream) {
    (void)in_sizes; (void)out_size; (void)d_ws; (void)ws_size;
    Params p;
    const int m = (n_in < 29) ? n_in : 29;
    for (int i = 0; i < m; ++i) p.in[i] = d_in[i];
    liquid_cfc_kernel<<<dim3(B_), dim3(256), 0, stream>>>(p, d_out);
}